// Round 12
// baseline (402.713 us; speedup 1.0000x reference)
//
#include <hip/hip_runtime.h>
#include <stdint.h>

namespace {

constexpr int kB = 32, kT = 576, kC = 1024, kH = 16, kD = 64;
constexpr int kM = kB * kT;        // 18432 rows
constexpr int kNqkv = 3 * kC;      // 3072
// Q pre-scale: 1/D for the reference's score scaling, times log2(e) so the
// attention softmax can use native v_exp_f32 (2^x) directly.
constexpr float kQScale = 1.4426950408889634f / 64.0f;

typedef uint16_t u16;
typedef __attribute__((ext_vector_type(4))) float f32x4;
typedef __attribute__((ext_vector_type(8))) short short8;
typedef __attribute__((ext_vector_type(8))) __bf16 bf16x8;
typedef __attribute__((ext_vector_type(4))) uint16_t u16x4;

#define VMCNT(n) asm volatile("s_waitcnt vmcnt(" #n ")" ::: "memory")

__device__ __forceinline__ float fexp2(float x) {
  return __builtin_amdgcn_exp2f(x);   // native v_exp_f32 (2^x)
}

__device__ __forceinline__ f32x4 mfma_bf16(short8 a, short8 b, f32x4 c) {
  return __builtin_amdgcn_mfma_f32_16x16x32_bf16(
      __builtin_bit_cast(bf16x8, a), __builtin_bit_cast(bf16x8, b), c, 0, 0, 0);
}

__device__ __forceinline__ u16 to_bf16(float x) {
  uint32_t u = __float_as_uint(x);
  u += 0x7fffu + ((u >> 16) & 1u);
  return (u16)(u >> 16);
}

__device__ __forceinline__ void gload_lds16(const void* g, void* l) {
  __builtin_amdgcn_global_load_lds(
      (const __attribute__((address_space(1))) uint32_t*)(uintptr_t)g,
      (__attribute__((address_space(3))) uint32_t*)(uintptr_t)l,
      16, 0, 0);
}

// raw barrier: no vmcnt drain. memory fences pin LDS/global ops on their side.
__device__ __forceinline__ void bar() {
  asm volatile("" ::: "memory");
  __builtin_amdgcn_s_barrier();
  asm volatile("" ::: "memory");
}

// ---- f32 -> bf16 flat cast ----
__global__ __launch_bounds__(256) void cvt_bf16_kernel(
    const float* __restrict__ in, u16* __restrict__ out, int n4) {
  const int i = blockIdx.x * 256 + threadIdx.x;
  if (i >= n4) return;
  const f32x4 v = ((const f32x4*)in)[i];
  u16x4 o;
#pragma unroll
  for (int j = 0; j < 4; ++j) o[j] = to_bf16(v[j]);
  ((u16x4*)out)[i] = o;
}

// ---- transpose-convert: in[K][N] f32 -> out[N][K] bf16 ----
__global__ void tconv_kernel(const float* __restrict__ in, u16* __restrict__ out,
                             int K, int N) {
  __shared__ u16 tile[32][33];
  const int nb = blockIdx.x * 32;
  const int kb = blockIdx.y * 32;
  const int tx = threadIdx.x;
  const int ty = threadIdx.y;
#pragma unroll
  for (int i = 0; i < 32; i += 8)
    tile[ty + i][tx] = to_bf16(in[(size_t)(kb + ty + i) * N + nb + tx]);
  __syncthreads();
#pragma unroll
  for (int i = 0; i < 32; i += 8)
    out[(size_t)(nb + ty + i) * K + kb + tx] = tile[tx][ty + i];
}

// ---- QKV GEMM (r11, validated): 256x128, BK=32, ring-3, 1 bar/tile,
//      2 blocks/CU ----
__global__ __launch_bounds__(512, 4) void gemm_qkv(
    const u16* __restrict__ A, const u16* __restrict__ Bt,
    const float* __restrict__ bias,
    u16* __restrict__ outQ, u16* __restrict__ outK, u16* __restrict__ outVT) {
  constexpr int Kc = 1024;
  constexpr int NT = Kc / 32;          // 32 K-tiles
  __shared__ char lds[3][24576];       // slot: A @0 (16KB), B @16384 (8KB)

  const int tid = threadIdx.x;
  const int wave = tid >> 6;
  const int lane = tid & 63;
  const int lo = lane & 15;
  const int hi = lane >> 4;
  const int wr = wave >> 1;            // 0..3 -> rows wr*64
  const int wc = wave & 1;             // 0..1 -> cols wc*64

  // XCD chunking: nwg = 24*72 = 1728 = 8 * 216 (bijective)
  const int lin = blockIdx.x + blockIdx.y * 24;
  const int l2 = (lin & 7) * 216 + (lin >> 3);
  const int n0 = (l2 % 24) * 128;
  const int m0 = (l2 / 24) * 256;

  // inverse-swizzled staging sources
  const u16* srcA[2];
#pragma unroll
  for (int c = 0; c < 2; ++c) {
    const int off = c * 8192 + tid * 16;
    const int p = off >> 7;                       // 0..127
    const int col = (off & 127) ^ ((p & 7) << 4);
    const int Ar = (col < 64) ? p : p + 128;
    const int k_ = (col & 63) >> 1;
    srcA[c] = A + (size_t)(m0 + Ar) * Kc + k_;
  }
  const u16* srcB1;
  {
    const int off = tid * 16;
    const int p = off >> 7;                       // 0..63
    const int col = (off & 127) ^ ((p & 7) << 4);
    const int Br = (col < 64) ? p : p + 64;
    const int k_ = (col & 63) >> 1;
    srcB1 = Bt + (size_t)(n0 + Br) * Kc + k_;
  }

  auto stage = [&](int slot, int t) {             // 3 gload_lds per thread
    char* base = &lds[slot][0];
    gload_lds16(srcA[0] + t * 32, base + tid * 16);
    gload_lds16(srcA[1] + t * 32, base + 8192 + tid * 16);
    gload_lds16(srcB1 + t * 32, base + 16384 + tid * 16);
  };

  f32x4 acc[4][4] = {};

  auto compute = [&](int slot) {
    const char* base = &lds[slot][0];
    const char* baseB = base + 16384;
    const int swz = (lo & 7) << 4;                // row&7 == lo&7 (rows = X*16+lo)
    short8 af[4], bf[4];
#pragma unroll
    for (int i = 0; i < 4; ++i) {
      const int row = wr * 64 + i * 16 + lo;      // 0..255
      const int prow = row & 127;
      const int half = row >> 7;
      af[i] = *(const short8*)(base + prow * 128 + ((half * 64 + hi * 16) ^ swz));
    }
#pragma unroll
    for (int j = 0; j < 4; ++j) {
      const int row = wc * 64 + j * 16 + lo;      // 0..127
      const int prow = row & 63;
      const int half = row >> 6;
      bf[j] = *(const short8*)(baseB + prow * 128 + ((half * 64 + hi * 16) ^ swz));
    }
    __builtin_amdgcn_s_setprio(1);
#pragma unroll
    for (int i = 0; i < 4; ++i)
#pragma unroll
      for (int j = 0; j < 4; ++j)
        acc[i][j] = mfma_bf16(af[i], bf[j], acc[i][j]);
    __builtin_amdgcn_s_setprio(0);
  };

  // 1-bar ring-3 pipeline, prefetch distance 2
  stage(0, 0);
  stage(1, 1);
  for (int t = 0; t < NT; ++t) {
    if (t + 1 < NT) { VMCNT(3); } else { VMCNT(0); }  // own tile-t landed
    bar();                                            // everyone's tile-t ready
    compute(t % 3);
    if (t + 2 < NT) stage((t + 2) % 3, t + 2);
  }
  bar();   // all waves done computing before epilogue reuses LDS

  // ---- epilogue. C/D frag: col = lo, row = hi*4 + r   [m89/m91]
  if (n0 >= 2048) {
    // V block: transpose through LDS (per-wave [32][66] u16, 2 passes),
    // store V^T [B,H,D,T] coalesced (8B/lane, 64 consecutive t per row).
    u16* wlds = (u16*)&lds[0][0] + wave * (32 * 66);
    uint32_t* wlds32 = (uint32_t*)wlds;
#pragma unroll
    for (int jp = 0; jp < 2; ++jp) {
#pragma unroll
      for (int jj = 0; jj < 2; ++jj) {
        const int j = jp * 2 + jj;
        const int n = n0 + wc * 64 + j * 16 + lo;
        const float bv = bias[n];
        const int dl = jj * 16 + lo;              // 0..31 local d row
#pragma unroll
        for (int i = 0; i < 4; ++i)
#pragma unroll
          for (int rp = 0; rp < 2; ++rp) {
            const u16 w0 = to_bf16(acc[i][j][rp * 2] + bv);
            const u16 w1 = to_bf16(acc[i][j][rp * 2 + 1] + bv);
            wlds32[dl * 33 + i * 8 + hi * 2 + rp] =
                (uint32_t)w0 | ((uint32_t)w1 << 16);
          }
      }
#pragma unroll
      for (int p = 0; p < 8; ++p) {
        const int dl32 = p * 4 + hi;              // 0..31
        const int n = n0 + wc * 64 + jp * 32 + dl32;
        const int c = n & 1023;
        const int hh = c >> 6;
        const int d = c & 63;
        const int m = m0 + wr * 64 + lo * 4;
        const int bb = m / kT;
        const int t = m - bb * kT;
        const u16x4 v = *(const u16x4*)&wlds[dl32 * 66 + lo * 4];
        *(u16x4*)&outVT[((size_t)(bb * kH + hh) * kD + d) * kT + t] = v;
      }
    }
  } else {
#pragma unroll
    for (int j = 0; j < 4; ++j) {
      const int n = n0 + wc * 64 + j * 16 + lo;
      const float bv = bias[n];
      const int which = n >> 10;                  // block-uniform (1024%128==0)
      const int c = n & 1023;
      const int hh = c >> 6;
      const int d = c & 63;
#pragma unroll
      for (int i = 0; i < 4; ++i) {
        const int mrow = m0 + wr * 64 + i * 16 + hi * 4;
#pragma unroll
        for (int r = 0; r < 4; ++r) {
          const int m = mrow + r;
          const int bb = m / kT;
          const int t = m - bb * kT;
          const float v = acc[i][j][r] + bv;
          if (which == 0)       // Q pre-scaled for exp2-softmax
            outQ[((size_t)(bb * kH + hh) * kT + t) * kD + d] = to_bf16(v * kQScale);
          else
            outK[((size_t)(bb * kH + hh) * kT + t) * kD + d] = to_bf16(v);
        }
      }
    }
  }
}

// ---- proj GEMM v4: 128x128, BK=32, 256 thr, ring-2 (32KB) -> 5 blocks/CU.
// Tail fix: 1152 blocks vs 1280 co-resident slots -> single occupancy round
// (was 576 blocks / 512 slots = 1.125 rounds, ~44% idle-CU integral).
// 4 waves (2M x 2N), per-wave 64x64, acc[4][4]. A and B tiles both packed
// [64 prow][128B] (col<64 -> row=prow, else prow+64), swz ^(prow&7)<<4.
// 4 gload_lds/thread/tile; counted VMCNT(4); r9's proven 2-bar loop (the
// stalls are hidden by 4 co-resident sibling blocks).
__global__ __launch_bounds__(256, 5) void gemm_proj(
    const u16* __restrict__ A, const u16* __restrict__ Bt,
    const float* __restrict__ bias, float* __restrict__ outF) {
  constexpr int Kc = 1024;
  constexpr int NT = Kc / 32;          // 32 K-tiles
  __shared__ char lds[2][16384];       // slot: A @0 (8KB), B @8192 (8KB)

  const int tid = threadIdx.x;
  const int wave = tid >> 6;
  const int lane = tid & 63;
  const int lo = lane & 15;
  const int hi = lane >> 4;
  const int wr = wave >> 1;            // 0..1 -> rows wr*64
  const int wc = wave & 1;             // 0..1 -> cols wc*64

  // XCD chunking: nwg = 8*144 = 1152 = 8 * 144 (bijective)
  const int lin = blockIdx.x + blockIdx.y * 8;
  const int l2 = (lin & 7) * 144 + (lin >> 3);
  const int n0 = (l2 % 8) * 128;
  const int m0 = (l2 / 8) * 128;

  // inverse-swizzled staging sources (A and B tiles identically packed)
  const u16* srcA[2];
  const u16* srcB[2];
#pragma unroll
  for (int c = 0; c < 2; ++c) {
    const int off = c * 4096 + tid * 16;
    const int p = off >> 7;                       // 0..63
    const int col = (off & 127) ^ ((p & 7) << 4);
    const int r_ = (col < 64) ? p : p + 64;
    const int k_ = (col & 63) >> 1;
    srcA[c] = A + (size_t)(m0 + r_) * Kc + k_;
    srcB[c] = Bt + (size_t)(n0 + r_) * Kc + k_;
  }

  auto stage = [&](int slot, int t) {             // 4 gload_lds per thread
    char* base = &lds[slot][0];
#pragma unroll
    for (int c = 0; c < 2; ++c) {
      gload_lds16(srcA[c] + t * 32, base + c * 4096 + tid * 16);
      gload_lds16(srcB[c] + t * 32, base + 8192 + c * 4096 + tid * 16);
    }
  };

  f32x4 acc[4][4] = {};

  auto compute = [&](int slot) {
    const char* base = &lds[slot][0];
    const char* baseB = base + 8192;
    const int swz = (lo & 7) << 4;
    short8 af[4], bf[4];
#pragma unroll
    for (int i = 0; i < 4; ++i) {
      const int row = wr * 64 + i * 16 + lo;      // 0..127
      const int prow = row & 63;
      const int half = row >> 6;
      af[i] = *(const short8*)(base + prow * 128 + ((half * 64 + hi * 16) ^ swz));
    }
#pragma unroll
    for (int j = 0; j < 4; ++j) {
      const int row = wc * 64 + j * 16 + lo;      // 0..127
      const int prow = row & 63;
      const int half = row >> 6;
      bf[j] = *(const short8*)(baseB + prow * 128 + ((half * 64 + hi * 16) ^ swz));
    }
    __builtin_amdgcn_s_setprio(1);
#pragma unroll
    for (int i = 0; i < 4; ++i)
#pragma unroll
      for (int j = 0; j < 4; ++j)
        acc[i][j] = mfma_bf16(af[i], bf[j], acc[i][j]);
    __builtin_amdgcn_s_setprio(0);
  };

  stage(0, 0);
  for (int t = 0; t < NT; ++t) {
    if (t + 1 < NT) {
      stage((t + 1) & 1, t + 1);
      VMCNT(4);                 // own tile-t loads landed; t+1's in flight
    } else {
      VMCNT(0);
    }
    bar();
    compute(t & 1);
    bar();
  }

#pragma unroll
  for (int j = 0; j < 4; ++j) {
    const int n = n0 + wc * 64 + j * 16 + lo;
    const float bv = bias[n];
#pragma unroll
    for (int i = 0; i < 4; ++i) {
      const int mrow = m0 + wr * 64 + i * 16 + hi * 4;
#pragma unroll
      for (int r = 0; r < 4; ++r)
        outF[(size_t)(mrow + r) * kC + n] = acc[i][j][r] + bv;
    }
  }
}

// ---- causal flash attention v4 (r10, validated) ----
__global__ __launch_bounds__(256) void attn_kernel(
    const u16* __restrict__ Q, const u16* __restrict__ K,
    const u16* __restrict__ VT, u16* __restrict__ Y) {
  __shared__ u16 P[4][32][72];   // per-wave P tile, 144B rows

  const int idx = blockIdx.x;
  const int qi = 4 - (idx >> 9);     // heavy-first
  const int bh = idx & 511;
  const int wave = threadIdx.x >> 6;
  const int lane = threadIdx.x & 63;
  const int lo = lane & 15;
  const int hi = lane >> 4;
  const int q0 = qi * 128 + wave * 32;
  if (q0 >= kT) return;

  const u16* Qb = Q + (size_t)bh * kT * kD;
  const u16* Kb = K + (size_t)bh * kT * kD;
  const u16* Vb = VT + (size_t)bh * kD * kT;

  short8 qf[2][2];
#pragma unroll
  for (int h = 0; h < 2; ++h) {
    const u16* qp = Qb + (q0 + h * 16 + lo) * kD + hi * 8;
    qf[h][0] = *(const short8*)qp;
    qf[h][1] = *(const short8*)(qp + 32);
  }

  f32x4 acc[2][4] = {};
  float mrun[2] = {-3e38f, -3e38f};
  float lsum[2] = {0.f, 0.f};

  short8 kf[4][2];
#pragma unroll
  for (int kc = 0; kc < 4; ++kc) {
    const u16* kp = Kb + (kc * 16 + lo) * kD + hi * 8;
    kf[kc][0] = *(const short8*)kp;
    kf[kc][1] = *(const short8*)(kp + 32);
  }

  const int nfull = q0 >> 6;               // fully-unmasked 64-wide tiles
  const bool tail4 = ((q0 >> 5) & 1) != 0; // tail width: 64 if odd 32-step

  auto do_tile = [&](int kv, int kclim, bool masked, bool have_next,
                     bool next_wide) {
    f32x4 s[2][4];
#pragma unroll
    for (int kc = 0; kc < 4; ++kc) {
      if (kc < kclim) {
#pragma unroll
        for (int h = 0; h < 2; ++h) {
          f32x4 z = {0.f, 0.f, 0.f, 0.f};
          z = mfma_bf16(kf[kc][0], qf[h][0], z);
          z = mfma_bf16(kf[kc][1], qf[h][1], z);
          s[h][kc] = z;
        }
      }
    }
    short8 vf[4][2];
#pragma unroll
    for (int nt = 0; nt < 4; ++nt) {
      const u16* vp = Vb + (nt * 16 + lo) * kT + kv + hi * 8;
      vf[nt][0] = *(const short8*)vp;
      if (kclim == 4) vf[nt][1] = *(const short8*)(vp + 32);
    }
    if (have_next) {
#pragma unroll
      for (int kc = 0; kc < 2; ++kc) {
        const u16* kp = Kb + (kv + 64 + kc * 16 + lo) * kD + hi * 8;
        kf[kc][0] = *(const short8*)kp;
        kf[kc][1] = *(const short8*)(kp + 32);
      }
      if (next_wide) {
#pragma unroll
        for (int kc = 2; kc < 4; ++kc) {
          const u16* kp = Kb + (kv + 64 + kc * 16 + lo) * kD + hi * 8;
          kf[kc][0] = *(const short8*)kp;
          kf[kc][1] = *(const short8*)(kp + 32);
        }
      }
    }
    if (masked) {
#pragma unroll
      for (int h = 0; h < 2; ++h) {
        const int q = q0 + h * 16 + lo;
#pragma unroll
        for (int kc = 0; kc < 4; ++kc)
          if (kc < kclim) {
#pragma unroll
            for (int r = 0; r < 4; ++r)
              if (kv + kc * 16 + hi * 4 + r > q) s[h][kc][r] = -3e38f;
          }
      }
    }
#pragma unroll
    for (int h = 0; h < 2; ++h) {
      float pm;
      {
        float m01 = fmaxf(fmaxf(s[h][0][0], s[h][0][1]),
                          fmaxf(s[h][0][2], s[h][0][3]));
        float m23 = fmaxf(fmaxf(s[h][1][0], s[h][1][1]),
                          fmaxf(s[h][1][2], s[h][1][3]));
        pm = fmaxf(m01, m23);
        if (kclim == 4) {
          float m45 = fmaxf(fmaxf(s[h][2][0], s[h][2][1]),
                            fmaxf(s[h][2][2], s[h][2][3]));
          float m67 = fmaxf(fmaxf(s[h][3][0], s[h][3][1]),
                            fmaxf(s[h][3][2], s[h][3][3]));
          pm = fmaxf(pm, fmaxf(m45, m67));
        }
      }
      pm = fmaxf(pm, __shfl_xor(pm, 16));
      pm = fmaxf(pm, __shfl_xor(pm, 32));
      const float mnew = fmaxf(mrun[h], pm);
      const float corr = fexp2(mrun[h] - mnew);
      mrun[h] = mnew;
      float psum = 0.f;
#pragma unroll
      for (int kc = 0; kc < 4; ++kc)
        if (kc < kclim) {
          u16x4 pk;
#pragma unroll
          for (int r = 0; r < 4; ++r) {
            const float pv = fexp2(s[h][kc][r] - mnew);
            psum += pv;
            pk[r] = to_bf16(pv);
          }
          *(u16x4*)&P[wave][h * 16 + lo][kc * 16 + hi * 4] = pk;
        }
      lsum[h] = lsum[h] * corr + psum;
#pragma unroll
      for (int nt = 0; nt < 4; ++nt)
#pragma unroll
        for (int r = 0; r < 4; ++r) acc[h][nt][r] *= corr;
      const short8 pf0 = *(const short8*)&P[wave][h * 16 + lo][hi * 8];
      short8 pf1;
      if (kclim == 4) pf1 = *(const short8*)&P[wave][h * 16 + lo][32 + hi * 8];
#pragma unroll
      for (int nt = 0; nt < 4; ++nt) {
        acc[h][nt] = mfma_bf16(pf0, vf[nt][0], acc[h][nt]);
        if (kclim == 4) acc[h][nt] = mfma_bf16(pf1, vf[nt][1], acc[h][nt]);
      }
    }
  };

  for (int it = 0; it < nfull; ++it)
    do_tile(it * 64, 4, false, true, (it + 1 < nfull) || tail4);
  if (tail4) do_tile(nfull * 64, 4, true, false, false);
  else       do_tile(nfull * 64, 2, true, false, false);

#pragma unroll
  for (int h = 0; h < 2; ++h) {
    lsum[h] += __shfl_xor(lsum[h], 16);
    lsum[h] += __shfl_xor(lsum[h], 32);
  }
  const int b = bh >> 4, hh = bh & 15;
#pragma unroll
  for (int h = 0; h < 2; ++h)
#pragma unroll
    for (int r = 0; r < 4; ++r) {
      const float linv = 1.0f / __shfl(lsum[h], hi * 4 + r);
      const int t = q0 + h * 16 + hi * 4 + r;
      const size_t base = ((size_t)(b * kT + t) * kH + hh) * kD;
#pragma unroll
      for (int nt = 0; nt < 4; ++nt)
        Y[base + nt * 16 + lo] = to_bf16(acc[h][nt][r] * linv);
    }
}

}  // namespace

extern "C" void kernel_launch(void* const* d_in, const int* in_sizes, int n_in,
                              void* d_out, int out_size, void* d_ws, size_t ws_size,
                              hipStream_t stream) {
  (void)in_sizes; (void)n_in; (void)out_size; (void)ws_size;
  const float* emb   = (const float*)d_in[0];
  const float* wqkv  = (const float*)d_in[1];
  const float* bqkv  = (const float*)d_in[2];
  const float* wproj = (const float*)d_in[3];
  const float* bproj = (const float*)d_in[4];
  float* out = (float*)d_out;

  char* p = (char*)d_ws;
  u16* embb   = (u16*)p; p += (size_t)kM * kC * 2;
  u16* wqkvt  = (u16*)p; p += (size_t)kNqkv * kC * 2;
  u16* wprojt = (u16*)p; p += (size_t)kC * kC * 2;
  u16* Qh     = (u16*)p; p += (size_t)kM * kC * 2;
  u16* Kh     = (u16*)p; p += (size_t)kM * kC * 2;
  u16* VTh    = (u16*)p; p += (size_t)kM * kC * 2;
  u16* Yh     = (u16*)p; p += (size_t)kM * kC * 2;

  const int n4 = kM * kC / 4;
  cvt_bf16_kernel<<<dim3((n4 + 255) / 256), 256, 0, stream>>>(emb, embb, n4);
  tconv_kernel<<<dim3(kNqkv / 32, kC / 32), dim3(32, 8), 0, stream>>>(wqkv, wqkvt, kC, kNqkv);
  tconv_kernel<<<dim3(kC / 32, kC / 32), dim3(32, 8), 0, stream>>>(wproj, wprojt, kC, kC);
  gemm_qkv<<<dim3(kNqkv / 128, kM / 256), 512, 0, stream>>>(
      embb, wqkvt, bqkv, Qh, Kh, VTh);
  attn_kernel<<<dim3(5 * kB * kH), 256, 0, stream>>>(Qh, Kh, VTh, Yh);
  gemm_proj<<<dim3(8, kM / 128), 256, 0, stream>>>(
      Yh, wprojt, bproj, out);
}

// Round 13
// 321.928 us; speedup vs baseline: 1.2509x; 1.2509x over previous
//
#include <hip/hip_runtime.h>
#include <stdint.h>

namespace {

constexpr int kB = 32, kT = 576, kC = 1024, kH = 16, kD = 64;
constexpr int kM = kB * kT;        // 18432 rows
constexpr int kNqkv = 3 * kC;      // 3072
// Q pre-scale: 1/D for the reference's score scaling, times log2(e) so the
// attention softmax can use native v_exp_f32 (2^x) directly.
constexpr float kQScale = 1.4426950408889634f / 64.0f;

typedef uint16_t u16;
typedef __attribute__((ext_vector_type(4))) float f32x4;
typedef __attribute__((ext_vector_type(8))) short short8;
typedef __attribute__((ext_vector_type(8))) __bf16 bf16x8;
typedef __attribute__((ext_vector_type(4))) uint16_t u16x4;

#define VMCNT(n) asm volatile("s_waitcnt vmcnt(" #n ")" ::: "memory")

__device__ __forceinline__ float fexp2(float x) {
  return __builtin_amdgcn_exp2f(x);   // native v_exp_f32 (2^x)
}

__device__ __forceinline__ f32x4 mfma_bf16(short8 a, short8 b, f32x4 c) {
  return __builtin_amdgcn_mfma_f32_16x16x32_bf16(
      __builtin_bit_cast(bf16x8, a), __builtin_bit_cast(bf16x8, b), c, 0, 0, 0);
}

__device__ __forceinline__ u16 to_bf16(float x) {
  uint32_t u = __float_as_uint(x);
  u += 0x7fffu + ((u >> 16) & 1u);
  return (u16)(u >> 16);
}

__device__ __forceinline__ void gload_lds16(const void* g, void* l) {
  __builtin_amdgcn_global_load_lds(
      (const __attribute__((address_space(1))) uint32_t*)(uintptr_t)g,
      (__attribute__((address_space(3))) uint32_t*)(uintptr_t)l,
      16, 0, 0);
}

// raw barrier: no vmcnt drain. memory fences pin LDS/global ops on their side.
__device__ __forceinline__ void bar() {
  asm volatile("" ::: "memory");
  __builtin_amdgcn_s_barrier();
  asm volatile("" ::: "memory");
}

// ---- f32 -> bf16 flat cast ----
__global__ __launch_bounds__(256) void cvt_bf16_kernel(
    const float* __restrict__ in, u16* __restrict__ out, int n4) {
  const int i = blockIdx.x * 256 + threadIdx.x;
  if (i >= n4) return;
  const f32x4 v = ((const f32x4*)in)[i];
  u16x4 o;
#pragma unroll
  for (int j = 0; j < 4; ++j) o[j] = to_bf16(v[j]);
  ((u16x4*)out)[i] = o;
}

// ---- transpose-convert: in[K][N] f32 -> out[N][K] bf16 ----
__global__ void tconv_kernel(const float* __restrict__ in, u16* __restrict__ out,
                             int K, int N) {
  __shared__ u16 tile[32][33];
  const int nb = blockIdx.x * 32;
  const int kb = blockIdx.y * 32;
  const int tx = threadIdx.x;
  const int ty = threadIdx.y;
#pragma unroll
  for (int i = 0; i < 32; i += 8)
    tile[ty + i][tx] = to_bf16(in[(size_t)(kb + ty + i) * N + nb + tx]);
  __syncthreads();
#pragma unroll
  for (int i = 0; i < 32; i += 8)
    out[(size_t)(nb + ty + i) * K + kb + tx] = tile[tx][ty + i];
}

// ---- QKV GEMM (r11, measured 139.0-139.6us): 256x128, BK=32, ring-3,
//      1 bar/tile, 2 blocks/CU ----
__global__ __launch_bounds__(512, 4) void gemm_qkv(
    const u16* __restrict__ A, const u16* __restrict__ Bt,
    const float* __restrict__ bias,
    u16* __restrict__ outQ, u16* __restrict__ outK, u16* __restrict__ outVT) {
  constexpr int Kc = 1024;
  constexpr int NT = Kc / 32;          // 32 K-tiles
  __shared__ char lds[3][24576];       // slot: A @0 (16KB), B @16384 (8KB)

  const int tid = threadIdx.x;
  const int wave = tid >> 6;
  const int lane = tid & 63;
  const int lo = lane & 15;
  const int hi = lane >> 4;
  const int wr = wave >> 1;            // 0..3 -> rows wr*64
  const int wc = wave & 1;             // 0..1 -> cols wc*64

  // XCD chunking: nwg = 24*72 = 1728 = 8 * 216 (bijective)
  const int lin = blockIdx.x + blockIdx.y * 24;
  const int l2 = (lin & 7) * 216 + (lin >> 3);
  const int n0 = (l2 % 24) * 128;
  const int m0 = (l2 / 24) * 256;

  // inverse-swizzled staging sources
  const u16* srcA[2];
#pragma unroll
  for (int c = 0; c < 2; ++c) {
    const int off = c * 8192 + tid * 16;
    const int p = off >> 7;                       // 0..127
    const int col = (off & 127) ^ ((p & 7) << 4);
    const int Ar = (col < 64) ? p : p + 128;
    const int k_ = (col & 63) >> 1;
    srcA[c] = A + (size_t)(m0 + Ar) * Kc + k_;
  }
  const u16* srcB1;
  {
    const int off = tid * 16;
    const int p = off >> 7;                       // 0..63
    const int col = (off & 127) ^ ((p & 7) << 4);
    const int Br = (col < 64) ? p : p + 64;
    const int k_ = (col & 63) >> 1;
    srcB1 = Bt + (size_t)(n0 + Br) * Kc + k_;
  }

  auto stage = [&](int slot, int t) {             // 3 gload_lds per thread
    char* base = &lds[slot][0];
    gload_lds16(srcA[0] + t * 32, base + tid * 16);
    gload_lds16(srcA[1] + t * 32, base + 8192 + tid * 16);
    gload_lds16(srcB1 + t * 32, base + 16384 + tid * 16);
  };

  f32x4 acc[4][4] = {};

  auto compute = [&](int slot) {
    const char* base = &lds[slot][0];
    const char* baseB = base + 16384;
    const int swz = (lo & 7) << 4;                // row&7 == lo&7 (rows = X*16+lo)
    short8 af[4], bf[4];
#pragma unroll
    for (int i = 0; i < 4; ++i) {
      const int row = wr * 64 + i * 16 + lo;      // 0..255
      const int prow = row & 127;
      const int half = row >> 7;
      af[i] = *(const short8*)(base + prow * 128 + ((half * 64 + hi * 16) ^ swz));
    }
#pragma unroll
    for (int j = 0; j < 4; ++j) {
      const int row = wc * 64 + j * 16 + lo;      // 0..127
      const int prow = row & 63;
      const int half = row >> 6;
      bf[j] = *(const short8*)(baseB + prow * 128 + ((half * 64 + hi * 16) ^ swz));
    }
    __builtin_amdgcn_s_setprio(1);
#pragma unroll
    for (int i = 0; i < 4; ++i)
#pragma unroll
      for (int j = 0; j < 4; ++j)
        acc[i][j] = mfma_bf16(af[i], bf[j], acc[i][j]);
    __builtin_amdgcn_s_setprio(0);
  };

  // 1-bar ring-3 pipeline, prefetch distance 2
  stage(0, 0);
  stage(1, 1);
  for (int t = 0; t < NT; ++t) {
    if (t + 1 < NT) { VMCNT(3); } else { VMCNT(0); }  // own tile-t landed
    bar();                                            // everyone's tile-t ready
    compute(t % 3);
    if (t + 2 < NT) stage((t + 2) % 3, t + 2);
  }
  bar();   // all waves done computing before epilogue reuses LDS

  // ---- epilogue. C/D frag: col = lo, row = hi*4 + r   [m89/m91]
  if (n0 >= 2048) {
    // V block: transpose through LDS (per-wave [32][66] u16, 2 passes),
    // store V^T [B,H,D,T] coalesced (8B/lane, 64 consecutive t per row).
    u16* wlds = (u16*)&lds[0][0] + wave * (32 * 66);
    uint32_t* wlds32 = (uint32_t*)wlds;
#pragma unroll
    for (int jp = 0; jp < 2; ++jp) {
#pragma unroll
      for (int jj = 0; jj < 2; ++jj) {
        const int j = jp * 2 + jj;
        const int n = n0 + wc * 64 + j * 16 + lo;
        const float bv = bias[n];
        const int dl = jj * 16 + lo;              // 0..31 local d row
#pragma unroll
        for (int i = 0; i < 4; ++i)
#pragma unroll
          for (int rp = 0; rp < 2; ++rp) {
            const u16 w0 = to_bf16(acc[i][j][rp * 2] + bv);
            const u16 w1 = to_bf16(acc[i][j][rp * 2 + 1] + bv);
            wlds32[dl * 33 + i * 8 + hi * 2 + rp] =
                (uint32_t)w0 | ((uint32_t)w1 << 16);
          }
      }
#pragma unroll
      for (int p = 0; p < 8; ++p) {
        const int dl32 = p * 4 + hi;              // 0..31
        const int n = n0 + wc * 64 + jp * 32 + dl32;
        const int c = n & 1023;
        const int hh = c >> 6;
        const int d = c & 63;
        const int m = m0 + wr * 64 + lo * 4;
        const int bb = m / kT;
        const int t = m - bb * kT;
        const u16x4 v = *(const u16x4*)&wlds[dl32 * 66 + lo * 4];
        *(u16x4*)&outVT[((size_t)(bb * kH + hh) * kD + d) * kT + t] = v;
      }
    }
  } else {
#pragma unroll
    for (int j = 0; j < 4; ++j) {
      const int n = n0 + wc * 64 + j * 16 + lo;
      const float bv = bias[n];
      const int which = n >> 10;                  // block-uniform (1024%128==0)
      const int c = n & 1023;
      const int hh = c >> 6;
      const int d = c & 63;
#pragma unroll
      for (int i = 0; i < 4; ++i) {
        const int mrow = m0 + wr * 64 + i * 16 + hi * 4;
#pragma unroll
        for (int r = 0; r < 4; ++r) {
          const int m = mrow + r;
          const int bb = m / kT;
          const int t = m - bb * kT;
          const float v = acc[i][j][r] + bv;
          if (which == 0)       // Q pre-scaled for exp2-softmax
            outQ[((size_t)(bb * kH + hh) * kT + t) * kD + d] = to_bf16(v * kQScale);
          else
            outK[((size_t)(bb * kH + hh) * kT + t) * kD + d] = to_bf16(v);
        }
      }
    }
  }
}

// ---- proj GEMM v2 (r10, part of the 316.25us best total): r9-structure
//      256x128, BK=32, ring-2, 512 thr, 2 blocks/CU, f32 +bias epilogue.
//      Grid 576 = 8*72 bijective XCD chunking.
__global__ __launch_bounds__(512, 4) void gemm_proj(
    const u16* __restrict__ A, const u16* __restrict__ Bt,
    const float* __restrict__ bias, float* __restrict__ outF) {
  constexpr int Kc = 1024;
  constexpr int NT = Kc / 32;          // 32 K-tiles
  __shared__ char lds[2][24576];       // slot: A @0 (16KB), B @16384 (8KB)

  const int tid = threadIdx.x;
  const int wave = tid >> 6;
  const int lane = tid & 63;
  const int lo = lane & 15;
  const int hi = lane >> 4;
  const int wr = wave >> 1;            // 0..3 -> rows wr*64
  const int wc = wave & 1;             // 0..1 -> cols wc*64

  // XCD chunking: nwg = 8*72 = 576 = 8 * 72 (bijective)
  const int lin = blockIdx.x + blockIdx.y * 8;
  const int l2 = (lin & 7) * 72 + (lin >> 3);
  const int n0 = (l2 % 8) * 128;
  const int m0 = (l2 / 8) * 256;

  const u16* srcA[2];
#pragma unroll
  for (int c = 0; c < 2; ++c) {
    const int off = c * 8192 + tid * 16;
    const int p = off >> 7;
    const int col = (off & 127) ^ ((p & 7) << 4);
    const int Ar = (col < 64) ? p : p + 128;
    const int k_ = (col & 63) >> 1;
    srcA[c] = A + (size_t)(m0 + Ar) * Kc + k_;
  }
  const u16* srcB1;
  {
    const int off = tid * 16;
    const int p = off >> 7;
    const int col = (off & 127) ^ ((p & 7) << 4);
    const int Br = (col < 64) ? p : p + 64;
    const int k_ = (col & 63) >> 1;
    srcB1 = Bt + (size_t)(n0 + Br) * Kc + k_;
  }

  auto stage = [&](int slot, int t) {
    char* base = &lds[slot][0];
    gload_lds16(srcA[0] + t * 32, base + tid * 16);
    gload_lds16(srcA[1] + t * 32, base + 8192 + tid * 16);
    gload_lds16(srcB1 + t * 32, base + 16384 + tid * 16);
  };

  f32x4 acc[4][4] = {};

  auto compute = [&](int slot) {
    const char* base = &lds[slot][0];
    const char* baseB = base + 16384;
    const int swz = (lo & 7) << 4;
    short8 af[4], bf[4];
#pragma unroll
    for (int i = 0; i < 4; ++i) {
      const int row = wr * 64 + i * 16 + lo;
      const int prow = row & 127;
      const int half = row >> 7;
      af[i] = *(const short8*)(base + prow * 128 + ((half * 64 + hi * 16) ^ swz));
    }
#pragma unroll
    for (int j = 0; j < 4; ++j) {
      const int row = wc * 64 + j * 16 + lo;
      const int prow = row & 63;
      const int half = row >> 6;
      bf[j] = *(const short8*)(baseB + prow * 128 + ((half * 64 + hi * 16) ^ swz));
    }
    __builtin_amdgcn_s_setprio(1);
#pragma unroll
    for (int i = 0; i < 4; ++i)
#pragma unroll
      for (int j = 0; j < 4; ++j)
        acc[i][j] = mfma_bf16(af[i], bf[j], acc[i][j]);
    __builtin_amdgcn_s_setprio(0);
  };

  stage(0, 0);
  for (int t = 0; t < NT; ++t) {
    if (t + 1 < NT) {
      stage((t + 1) & 1, t + 1);
      VMCNT(3);
    } else {
      VMCNT(0);
    }
    bar();
    compute(t & 1);
    bar();
  }

#pragma unroll
  for (int j = 0; j < 4; ++j) {
    const int n = n0 + wc * 64 + j * 16 + lo;
    const float bv = bias[n];
#pragma unroll
    for (int i = 0; i < 4; ++i) {
      const int mrow = m0 + wr * 64 + i * 16 + hi * 4;
#pragma unroll
      for (int r = 0; r < 4; ++r)
        outF[(size_t)(mrow + r) * kC + n] = acc[i][j][r] + bv;
    }
  }
}

// ---- causal flash attention v4 (r10, validated) ----
__global__ __launch_bounds__(256) void attn_kernel(
    const u16* __restrict__ Q, const u16* __restrict__ K,
    const u16* __restrict__ VT, u16* __restrict__ Y) {
  __shared__ u16 P[4][32][72];   // per-wave P tile, 144B rows

  const int idx = blockIdx.x;
  const int qi = 4 - (idx >> 9);     // heavy-first
  const int bh = idx & 511;
  const int wave = threadIdx.x >> 6;
  const int lane = threadIdx.x & 63;
  const int lo = lane & 15;
  const int hi = lane >> 4;
  const int q0 = qi * 128 + wave * 32;
  if (q0 >= kT) return;

  const u16* Qb = Q + (size_t)bh * kT * kD;
  const u16* Kb = K + (size_t)bh * kT * kD;
  const u16* Vb = VT + (size_t)bh * kD * kT;

  short8 qf[2][2];
#pragma unroll
  for (int h = 0; h < 2; ++h) {
    const u16* qp = Qb + (q0 + h * 16 + lo) * kD + hi * 8;
    qf[h][0] = *(const short8*)qp;
    qf[h][1] = *(const short8*)(qp + 32);
  }

  f32x4 acc[2][4] = {};
  float mrun[2] = {-3e38f, -3e38f};
  float lsum[2] = {0.f, 0.f};

  short8 kf[4][2];
#pragma unroll
  for (int kc = 0; kc < 4; ++kc) {
    const u16* kp = Kb + (kc * 16 + lo) * kD + hi * 8;
    kf[kc][0] = *(const short8*)kp;
    kf[kc][1] = *(const short8*)(kp + 32);
  }

  const int nfull = q0 >> 6;               // fully-unmasked 64-wide tiles
  const bool tail4 = ((q0 >> 5) & 1) != 0; // tail width: 64 if odd 32-step

  auto do_tile = [&](int kv, int kclim, bool masked, bool have_next,
                     bool next_wide) {
    f32x4 s[2][4];
#pragma unroll
    for (int kc = 0; kc < 4; ++kc) {
      if (kc < kclim) {
#pragma unroll
        for (int h = 0; h < 2; ++h) {
          f32x4 z = {0.f, 0.f, 0.f, 0.f};
          z = mfma_bf16(kf[kc][0], qf[h][0], z);
          z = mfma_bf16(kf[kc][1], qf[h][1], z);
          s[h][kc] = z;
        }
      }
    }
    short8 vf[4][2];
#pragma unroll
    for (int nt = 0; nt < 4; ++nt) {
      const u16* vp = Vb + (nt * 16 + lo) * kT + kv + hi * 8;
      vf[nt][0] = *(const short8*)vp;
      if (kclim == 4) vf[nt][1] = *(const short8*)(vp + 32);
    }
    if (have_next) {
#pragma unroll
      for (int kc = 0; kc < 2; ++kc) {
        const u16* kp = Kb + (kv + 64 + kc * 16 + lo) * kD + hi * 8;
        kf[kc][0] = *(const short8*)kp;
        kf[kc][1] = *(const short8*)(kp + 32);
      }
      if (next_wide) {
#pragma unroll
        for (int kc = 2; kc < 4; ++kc) {
          const u16* kp = Kb + (kv + 64 + kc * 16 + lo) * kD + hi * 8;
          kf[kc][0] = *(const short8*)kp;
          kf[kc][1] = *(const short8*)(kp + 32);
        }
      }
    }
    if (masked) {
#pragma unroll
      for (int h = 0; h < 2; ++h) {
        const int q = q0 + h * 16 + lo;
#pragma unroll
        for (int kc = 0; kc < 4; ++kc)
          if (kc < kclim) {
#pragma unroll
            for (int r = 0; r < 4; ++r)
              if (kv + kc * 16 + hi * 4 + r > q) s[h][kc][r] = -3e38f;
          }
      }
    }
#pragma unroll
    for (int h = 0; h < 2; ++h) {
      float pm;
      {
        float m01 = fmaxf(fmaxf(s[h][0][0], s[h][0][1]),
                          fmaxf(s[h][0][2], s[h][0][3]));
        float m23 = fmaxf(fmaxf(s[h][1][0], s[h][1][1]),
                          fmaxf(s[h][1][2], s[h][1][3]));
        pm = fmaxf(m01, m23);
        if (kclim == 4) {
          float m45 = fmaxf(fmaxf(s[h][2][0], s[h][2][1]),
                            fmaxf(s[h][2][2], s[h][2][3]));
          float m67 = fmaxf(fmaxf(s[h][3][0], s[h][3][1]),
                            fmaxf(s[h][3][2], s[h][3][3]));
          pm = fmaxf(pm, fmaxf(m45, m67));
        }
      }
      pm = fmaxf(pm, __shfl_xor(pm, 16));
      pm = fmaxf(pm, __shfl_xor(pm, 32));
      const float mnew = fmaxf(mrun[h], pm);
      const float corr = fexp2(mrun[h] - mnew);
      mrun[h] = mnew;
      float psum = 0.f;
#pragma unroll
      for (int kc = 0; kc < 4; ++kc)
        if (kc < kclim) {
          u16x4 pk;
#pragma unroll
          for (int r = 0; r < 4; ++r) {
            const float pv = fexp2(s[h][kc][r] - mnew);
            psum += pv;
            pk[r] = to_bf16(pv);
          }
          *(u16x4*)&P[wave][h * 16 + lo][kc * 16 + hi * 4] = pk;
        }
      lsum[h] = lsum[h] * corr + psum;
#pragma unroll
      for (int nt = 0; nt < 4; ++nt)
#pragma unroll
        for (int r = 0; r < 4; ++r) acc[h][nt][r] *= corr;
      const short8 pf0 = *(const short8*)&P[wave][h * 16 + lo][hi * 8];
      short8 pf1;
      if (kclim == 4) pf1 = *(const short8*)&P[wave][h * 16 + lo][32 + hi * 8];
#pragma unroll
      for (int nt = 0; nt < 4; ++nt) {
        acc[h][nt] = mfma_bf16(pf0, vf[nt][0], acc[h][nt]);
        if (kclim == 4) acc[h][nt] = mfma_bf16(pf1, vf[nt][1], acc[h][nt]);
      }
    }
  };

  for (int it = 0; it < nfull; ++it)
    do_tile(it * 64, 4, false, true, (it + 1 < nfull) || tail4);
  if (tail4) do_tile(nfull * 64, 4, true, false, false);
  else       do_tile(nfull * 64, 2, true, false, false);

#pragma unroll
  for (int h = 0; h < 2; ++h) {
    lsum[h] += __shfl_xor(lsum[h], 16);
    lsum[h] += __shfl_xor(lsum[h], 32);
  }
  const int b = bh >> 4, hh = bh & 15;
#pragma unroll
  for (int h = 0; h < 2; ++h)
#pragma unroll
    for (int r = 0; r < 4; ++r) {
      const float linv = 1.0f / __shfl(lsum[h], hi * 4 + r);
      const int t = q0 + h * 16 + hi * 4 + r;
      const size_t base = ((size_t)(b * kT + t) * kH + hh) * kD;
#pragma unroll
      for (int nt = 0; nt < 4; ++nt)
        Y[base + nt * 16 + lo] = to_bf16(acc[h][nt][r] * linv);
    }
}

}  // namespace

extern "C" void kernel_launch(void* const* d_in, const int* in_sizes, int n_in,
                              void* d_out, int out_size, void* d_ws, size_t ws_size,
                              hipStream_t stream) {
  (void)in_sizes; (void)n_in; (void)out_size; (void)ws_size;
  const float* emb   = (const float*)d_in[0];
  const float* wqkv  = (const float*)d_in[1];
  const float* bqkv  = (const float*)d_in[2];
  const float* wproj = (const float*)d_in[3];
  const float* bproj = (const float*)d_in[4];
  float* out = (float*)d_out;

  char* p = (char*)d_ws;
  u16* embb   = (u16*)p; p += (size_t)kM * kC * 2;
  u16* wqkvt  = (u16*)p; p += (size_t)kNqkv * kC * 2;
  u16* wprojt = (u16*)p; p += (size_t)kC * kC * 2;
  u16* Qh     = (u16*)p; p += (size_t)kM * kC * 2;
  u16* Kh     = (u16*)p; p += (size_t)kM * kC * 2;
  u16* VTh    = (u16*)p; p += (size_t)kM * kC * 2;
  u16* Yh     = (u16*)p; p += (size_t)kM * kC * 2;

  const int n4 = kM * kC / 4;
  cvt_bf16_kernel<<<dim3((n4 + 255) / 256), 256, 0, stream>>>(emb, embb, n4);
  tconv_kernel<<<dim3(kNqkv / 32, kC / 32), dim3(32, 8), 0, stream>>>(wqkv, wqkvt, kC, kNqkv);
  tconv_kernel<<<dim3(kC / 32, kC / 32), dim3(32, 8), 0, stream>>>(wproj, wprojt, kC, kC);
  gemm_qkv<<<dim3(kNqkv / 128, kM / 256), 512, 0, stream>>>(
      embb, wqkvt, bqkv, Qh, Kh, VTh);
  attn_kernel<<<dim3(5 * kB * kH), 256, 0, stream>>>(Qh, Kh, VTh, Yh);
  gemm_proj<<<dim3(kC / 128, kM / 256), 512, 0, stream>>>(
      Yh, wprojt, bproj, out);
}

// Round 14
// 315.861 us; speedup vs baseline: 1.2750x; 1.0192x over previous
//
#include <hip/hip_runtime.h>
#include <stdint.h>

namespace {

constexpr int kB = 32, kT = 576, kC = 1024, kH = 16, kD = 64;
constexpr int kM = kB * kT;        // 18432 rows
constexpr int kNqkv = 3 * kC;      // 3072
// Q pre-scale: 1/D for the reference's score scaling, times log2(e) so the
// attention softmax can use native v_exp_f32 (2^x) directly.
constexpr float kQScale = 1.4426950408889634f / 64.0f;

typedef uint16_t u16;
typedef __attribute__((ext_vector_type(4))) float f32x4;
typedef __attribute__((ext_vector_type(8))) short short8;
typedef __attribute__((ext_vector_type(8))) __bf16 bf16x8;
typedef __attribute__((ext_vector_type(4))) uint16_t u16x4;

#define VMCNT(n) asm volatile("s_waitcnt vmcnt(" #n ")" ::: "memory")

__device__ __forceinline__ float fexp2(float x) {
  return __builtin_amdgcn_exp2f(x);   // native v_exp_f32 (2^x)
}

__device__ __forceinline__ f32x4 mfma_bf16(short8 a, short8 b, f32x4 c) {
  return __builtin_amdgcn_mfma_f32_16x16x32_bf16(
      __builtin_bit_cast(bf16x8, a), __builtin_bit_cast(bf16x8, b), c, 0, 0, 0);
}

__device__ __forceinline__ u16 to_bf16(float x) {
  uint32_t u = __float_as_uint(x);
  u += 0x7fffu + ((u >> 16) & 1u);
  return (u16)(u >> 16);
}

__device__ __forceinline__ void gload_lds16(const void* g, void* l) {
  __builtin_amdgcn_global_load_lds(
      (const __attribute__((address_space(1))) uint32_t*)(uintptr_t)g,
      (__attribute__((address_space(3))) uint32_t*)(uintptr_t)l,
      16, 0, 0);
}

// raw barrier: no vmcnt drain. memory fences pin LDS/global ops on their side.
__device__ __forceinline__ void bar() {
  asm volatile("" ::: "memory");
  __builtin_amdgcn_s_barrier();
  asm volatile("" ::: "memory");
}

// ---- f32 -> bf16 flat cast ----
__global__ __launch_bounds__(256) void cvt_bf16_kernel(
    const float* __restrict__ in, u16* __restrict__ out, int n4) {
  const int i = blockIdx.x * 256 + threadIdx.x;
  if (i >= n4) return;
  const f32x4 v = ((const f32x4*)in)[i];
  u16x4 o;
#pragma unroll
  for (int j = 0; j < 4; ++j) o[j] = to_bf16(v[j]);
  ((u16x4*)out)[i] = o;
}

// ---- transpose-convert: in[K][N] f32 -> out[N][K] bf16 ----
__global__ void tconv_kernel(const float* __restrict__ in, u16* __restrict__ out,
                             int K, int N) {
  __shared__ u16 tile[32][33];
  const int nb = blockIdx.x * 32;
  const int kb = blockIdx.y * 32;
  const int tx = threadIdx.x;
  const int ty = threadIdx.y;
#pragma unroll
  for (int i = 0; i < 32; i += 8)
    tile[ty + i][tx] = to_bf16(in[(size_t)(kb + ty + i) * N + nb + tx]);
  __syncthreads();
#pragma unroll
  for (int i = 0; i < 32; i += 8)
    out[(size_t)(nb + ty + i) * K + kb + tx] = tile[tx][ty + i];
}

// ---- QKV GEMM (r9, part of best-measured 316.25us total): 256x128, BK=32,
//      ring-2 (48KB LDS), 2 blocks/CU, counted VMCNT(3) 2-bar loop ----
__global__ __launch_bounds__(512, 4) void gemm_qkv(
    const u16* __restrict__ A, const u16* __restrict__ Bt,
    const float* __restrict__ bias,
    u16* __restrict__ outQ, u16* __restrict__ outK, u16* __restrict__ outVT) {
  constexpr int Kc = 1024;
  constexpr int NT = Kc / 32;          // 32 K-tiles
  __shared__ char lds[2][24576];       // slot: A @0 (16KB), B @16384 (8KB)

  const int tid = threadIdx.x;
  const int wave = tid >> 6;
  const int lane = tid & 63;
  const int lo = lane & 15;
  const int hi = lane >> 4;
  const int wr = wave >> 1;            // 0..3 -> rows wr*64
  const int wc = wave & 1;             // 0..1 -> cols wc*64

  // XCD chunking: nwg = 24*72 = 1728 = 8 * 216 (bijective)
  const int lin = blockIdx.x + blockIdx.y * 24;
  const int l2 = (lin & 7) * 216 + (lin >> 3);
  const int n0 = (l2 % 24) * 128;
  const int m0 = (l2 / 24) * 256;

  // inverse-swizzled staging sources
  const u16* srcA[2];
#pragma unroll
  for (int c = 0; c < 2; ++c) {
    const int off = c * 8192 + tid * 16;
    const int p = off >> 7;                       // 0..127
    const int col = (off & 127) ^ ((p & 7) << 4);
    const int Ar = (col < 64) ? p : p + 128;
    const int k_ = (col & 63) >> 1;
    srcA[c] = A + (size_t)(m0 + Ar) * Kc + k_;
  }
  const u16* srcB1;
  {
    const int off = tid * 16;
    const int p = off >> 7;                       // 0..63
    const int col = (off & 127) ^ ((p & 7) << 4);
    const int Br = (col < 64) ? p : p + 64;
    const int k_ = (col & 63) >> 1;
    srcB1 = Bt + (size_t)(n0 + Br) * Kc + k_;
  }

  auto stage = [&](int slot, int t) {             // 3 gload_lds per thread
    char* base = &lds[slot][0];
    gload_lds16(srcA[0] + t * 32, base + tid * 16);
    gload_lds16(srcA[1] + t * 32, base + 8192 + tid * 16);
    gload_lds16(srcB1 + t * 32, base + 16384 + tid * 16);
  };

  f32x4 acc[4][4] = {};

  auto compute = [&](int slot) {
    const char* base = &lds[slot][0];
    const char* baseB = base + 16384;
    const int swz = (lo & 7) << 4;                // row&7 == lo&7 (rows = X*16+lo)
    short8 af[4], bf[4];
#pragma unroll
    for (int i = 0; i < 4; ++i) {
      const int row = wr * 64 + i * 16 + lo;      // 0..255
      const int prow = row & 127;
      const int half = row >> 7;
      af[i] = *(const short8*)(base + prow * 128 + ((half * 64 + hi * 16) ^ swz));
    }
#pragma unroll
    for (int j = 0; j < 4; ++j) {
      const int row = wc * 64 + j * 16 + lo;      // 0..127
      const int prow = row & 63;
      const int half = row >> 6;
      bf[j] = *(const short8*)(baseB + prow * 128 + ((half * 64 + hi * 16) ^ swz));
    }
    __builtin_amdgcn_s_setprio(1);
#pragma unroll
    for (int i = 0; i < 4; ++i)
#pragma unroll
      for (int j = 0; j < 4; ++j)
        acc[i][j] = mfma_bf16(af[i], bf[j], acc[i][j]);
    __builtin_amdgcn_s_setprio(0);
  };

  stage(0, 0);
  for (int t = 0; t < NT; ++t) {
    if (t + 1 < NT) {
      stage((t + 1) & 1, t + 1);
      VMCNT(3);                 // own tile-t loads landed; t+1's stay in flight
    } else {
      VMCNT(0);
    }
    bar();
    compute(t & 1);
    bar();
  }

  // ---- epilogue. C/D frag: col = lo, row = hi*4 + r   [m89/m91]
  if (n0 >= 2048) {
    // V block: transpose through LDS (per-wave [32][66] u16, 2 passes),
    // store V^T [B,H,D,T] coalesced (8B/lane, 64 consecutive t per row).
    u16* wlds = (u16*)&lds[0][0] + wave * (32 * 66);
    uint32_t* wlds32 = (uint32_t*)wlds;
#pragma unroll
    for (int jp = 0; jp < 2; ++jp) {
#pragma unroll
      for (int jj = 0; jj < 2; ++jj) {
        const int j = jp * 2 + jj;
        const int n = n0 + wc * 64 + j * 16 + lo;
        const float bv = bias[n];
        const int dl = jj * 16 + lo;              // 0..31 local d row
#pragma unroll
        for (int i = 0; i < 4; ++i)
#pragma unroll
          for (int rp = 0; rp < 2; ++rp) {
            const u16 w0 = to_bf16(acc[i][j][rp * 2] + bv);
            const u16 w1 = to_bf16(acc[i][j][rp * 2 + 1] + bv);
            wlds32[dl * 33 + i * 8 + hi * 2 + rp] =
                (uint32_t)w0 | ((uint32_t)w1 << 16);
          }
      }
#pragma unroll
      for (int p = 0; p < 8; ++p) {
        const int dl32 = p * 4 + hi;              // 0..31
        const int n = n0 + wc * 64 + jp * 32 + dl32;
        const int c = n & 1023;
        const int hh = c >> 6;
        const int d = c & 63;
        const int m = m0 + wr * 64 + lo * 4;
        const int bb = m / kT;
        const int t = m - bb * kT;
        const u16x4 v = *(const u16x4*)&wlds[dl32 * 66 + lo * 4];
        *(u16x4*)&outVT[((size_t)(bb * kH + hh) * kD + d) * kT + t] = v;
      }
    }
  } else {
#pragma unroll
    for (int j = 0; j < 4; ++j) {
      const int n = n0 + wc * 64 + j * 16 + lo;
      const float bv = bias[n];
      const int which = n >> 10;                  // block-uniform (1024%128==0)
      const int c = n & 1023;
      const int hh = c >> 6;
      const int d = c & 63;
#pragma unroll
      for (int i = 0; i < 4; ++i) {
        const int mrow = m0 + wr * 64 + i * 16 + hi * 4;
#pragma unroll
        for (int r = 0; r < 4; ++r) {
          const int m = mrow + r;
          const int bb = m / kT;
          const int t = m - bb * kT;
          const float v = acc[i][j][r] + bv;
          if (which == 0)       // Q pre-scaled for exp2-softmax
            outQ[((size_t)(bb * kH + hh) * kT + t) * kD + d] = to_bf16(v * kQScale);
          else
            outK[((size_t)(bb * kH + hh) * kT + t) * kD + d] = to_bf16(v);
        }
      }
    }
  }
}

// ---- proj GEMM v2 (r10, part of best-measured 316.25us total): r9-structure
//      256x128, BK=32, ring-2, 512 thr, 2 blocks/CU, f32 +bias epilogue.
//      Grid 576 = 8*72 bijective XCD chunking.
__global__ __launch_bounds__(512, 4) void gemm_proj(
    const u16* __restrict__ A, const u16* __restrict__ Bt,
    const float* __restrict__ bias, float* __restrict__ outF) {
  constexpr int Kc = 1024;
  constexpr int NT = Kc / 32;          // 32 K-tiles
  __shared__ char lds[2][24576];       // slot: A @0 (16KB), B @16384 (8KB)

  const int tid = threadIdx.x;
  const int wave = tid >> 6;
  const int lane = tid & 63;
  const int lo = lane & 15;
  const int hi = lane >> 4;
  const int wr = wave >> 1;            // 0..3 -> rows wr*64
  const int wc = wave & 1;             // 0..1 -> cols wc*64

  // XCD chunking: nwg = 8*72 = 576 = 8 * 72 (bijective)
  const int lin = blockIdx.x + blockIdx.y * 8;
  const int l2 = (lin & 7) * 72 + (lin >> 3);
  const int n0 = (l2 % 8) * 128;
  const int m0 = (l2 / 8) * 256;

  const u16* srcA[2];
#pragma unroll
  for (int c = 0; c < 2; ++c) {
    const int off = c * 8192 + tid * 16;
    const int p = off >> 7;
    const int col = (off & 127) ^ ((p & 7) << 4);
    const int Ar = (col < 64) ? p : p + 128;
    const int k_ = (col & 63) >> 1;
    srcA[c] = A + (size_t)(m0 + Ar) * Kc + k_;
  }
  const u16* srcB1;
  {
    const int off = tid * 16;
    const int p = off >> 7;
    const int col = (off & 127) ^ ((p & 7) << 4);
    const int Br = (col < 64) ? p : p + 64;
    const int k_ = (col & 63) >> 1;
    srcB1 = Bt + (size_t)(n0 + Br) * Kc + k_;
  }

  auto stage = [&](int slot, int t) {
    char* base = &lds[slot][0];
    gload_lds16(srcA[0] + t * 32, base + tid * 16);
    gload_lds16(srcA[1] + t * 32, base + 8192 + tid * 16);
    gload_lds16(srcB1 + t * 32, base + 16384 + tid * 16);
  };

  f32x4 acc[4][4] = {};

  auto compute = [&](int slot) {
    const char* base = &lds[slot][0];
    const char* baseB = base + 16384;
    const int swz = (lo & 7) << 4;
    short8 af[4], bf[4];
#pragma unroll
    for (int i = 0; i < 4; ++i) {
      const int row = wr * 64 + i * 16 + lo;
      const int prow = row & 127;
      const int half = row >> 7;
      af[i] = *(const short8*)(base + prow * 128 + ((half * 64 + hi * 16) ^ swz));
    }
#pragma unroll
    for (int j = 0; j < 4; ++j) {
      const int row = wc * 64 + j * 16 + lo;
      const int prow = row & 63;
      const int half = row >> 6;
      bf[j] = *(const short8*)(baseB + prow * 128 + ((half * 64 + hi * 16) ^ swz));
    }
    __builtin_amdgcn_s_setprio(1);
#pragma unroll
    for (int i = 0; i < 4; ++i)
#pragma unroll
      for (int j = 0; j < 4; ++j)
        acc[i][j] = mfma_bf16(af[i], bf[j], acc[i][j]);
    __builtin_amdgcn_s_setprio(0);
  };

  stage(0, 0);
  for (int t = 0; t < NT; ++t) {
    if (t + 1 < NT) {
      stage((t + 1) & 1, t + 1);
      VMCNT(3);
    } else {
      VMCNT(0);
    }
    bar();
    compute(t & 1);
    bar();
  }

#pragma unroll
  for (int j = 0; j < 4; ++j) {
    const int n = n0 + wc * 64 + j * 16 + lo;
    const float bv = bias[n];
#pragma unroll
    for (int i = 0; i < 4; ++i) {
      const int mrow = m0 + wr * 64 + i * 16 + hi * 4;
#pragma unroll
      for (int r = 0; r < 4; ++r)
        outF[(size_t)(mrow + r) * kC + n] = acc[i][j][r] + bv;
    }
  }
}

// ---- causal flash attention v4 (r10, validated) ----
__global__ __launch_bounds__(256) void attn_kernel(
    const u16* __restrict__ Q, const u16* __restrict__ K,
    const u16* __restrict__ VT, u16* __restrict__ Y) {
  __shared__ u16 P[4][32][72];   // per-wave P tile, 144B rows

  const int idx = blockIdx.x;
  const int qi = 4 - (idx >> 9);     // heavy-first
  const int bh = idx & 511;
  const int wave = threadIdx.x >> 6;
  const int lane = threadIdx.x & 63;
  const int lo = lane & 15;
  const int hi = lane >> 4;
  const int q0 = qi * 128 + wave * 32;
  if (q0 >= kT) return;

  const u16* Qb = Q + (size_t)bh * kT * kD;
  const u16* Kb = K + (size_t)bh * kT * kD;
  const u16* Vb = VT + (size_t)bh * kD * kT;

  short8 qf[2][2];
#pragma unroll
  for (int h = 0; h < 2; ++h) {
    const u16* qp = Qb + (q0 + h * 16 + lo) * kD + hi * 8;
    qf[h][0] = *(const short8*)qp;
    qf[h][1] = *(const short8*)(qp + 32);
  }

  f32x4 acc[2][4] = {};
  float mrun[2] = {-3e38f, -3e38f};
  float lsum[2] = {0.f, 0.f};

  short8 kf[4][2];
#pragma unroll
  for (int kc = 0; kc < 4; ++kc) {
    const u16* kp = Kb + (kc * 16 + lo) * kD + hi * 8;
    kf[kc][0] = *(const short8*)kp;
    kf[kc][1] = *(const short8*)(kp + 32);
  }

  const int nfull = q0 >> 6;               // fully-unmasked 64-wide tiles
  const bool tail4 = ((q0 >> 5) & 1) != 0; // tail width: 64 if odd 32-step

  auto do_tile = [&](int kv, int kclim, bool masked, bool have_next,
                     bool next_wide) {
    f32x4 s[2][4];
#pragma unroll
    for (int kc = 0; kc < 4; ++kc) {
      if (kc < kclim) {
#pragma unroll
        for (int h = 0; h < 2; ++h) {
          f32x4 z = {0.f, 0.f, 0.f, 0.f};
          z = mfma_bf16(kf[kc][0], qf[h][0], z);
          z = mfma_bf16(kf[kc][1], qf[h][1], z);
          s[h][kc] = z;
        }
      }
    }
    short8 vf[4][2];
#pragma unroll
    for (int nt = 0; nt < 4; ++nt) {
      const u16* vp = Vb + (nt * 16 + lo) * kT + kv + hi * 8;
      vf[nt][0] = *(const short8*)vp;
      if (kclim == 4) vf[nt][1] = *(const short8*)(vp + 32);
    }
    if (have_next) {
#pragma unroll
      for (int kc = 0; kc < 2; ++kc) {
        const u16* kp = Kb + (kv + 64 + kc * 16 + lo) * kD + hi * 8;
        kf[kc][0] = *(const short8*)kp;
        kf[kc][1] = *(const short8*)(kp + 32);
      }
      if (next_wide) {
#pragma unroll
        for (int kc = 2; kc < 4; ++kc) {
          const u16* kp = Kb + (kv + 64 + kc * 16 + lo) * kD + hi * 8;
          kf[kc][0] = *(const short8*)kp;
          kf[kc][1] = *(const short8*)(kp + 32);
        }
      }
    }
    if (masked) {
#pragma unroll
      for (int h = 0; h < 2; ++h) {
        const int q = q0 + h * 16 + lo;
#pragma unroll
        for (int kc = 0; kc < 4; ++kc)
          if (kc < kclim) {
#pragma unroll
            for (int r = 0; r < 4; ++r)
              if (kv + kc * 16 + hi * 4 + r > q) s[h][kc][r] = -3e38f;
          }
      }
    }
#pragma unroll
    for (int h = 0; h < 2; ++h) {
      float pm;
      {
        float m01 = fmaxf(fmaxf(s[h][0][0], s[h][0][1]),
                          fmaxf(s[h][0][2], s[h][0][3]));
        float m23 = fmaxf(fmaxf(s[h][1][0], s[h][1][1]),
                          fmaxf(s[h][1][2], s[h][1][3]));
        pm = fmaxf(m01, m23);
        if (kclim == 4) {
          float m45 = fmaxf(fmaxf(s[h][2][0], s[h][2][1]),
                            fmaxf(s[h][2][2], s[h][2][3]));
          float m67 = fmaxf(fmaxf(s[h][3][0], s[h][3][1]),
                            fmaxf(s[h][3][2], s[h][3][3]));
          pm = fmaxf(pm, fmaxf(m45, m67));
        }
      }
      pm = fmaxf(pm, __shfl_xor(pm, 16));
      pm = fmaxf(pm, __shfl_xor(pm, 32));
      const float mnew = fmaxf(mrun[h], pm);
      const float corr = fexp2(mrun[h] - mnew);
      mrun[h] = mnew;
      float psum = 0.f;
#pragma unroll
      for (int kc = 0; kc < 4; ++kc)
        if (kc < kclim) {
          u16x4 pk;
#pragma unroll
          for (int r = 0; r < 4; ++r) {
            const float pv = fexp2(s[h][kc][r] - mnew);
            psum += pv;
            pk[r] = to_bf16(pv);
          }
          *(u16x4*)&P[wave][h * 16 + lo][kc * 16 + hi * 4] = pk;
        }
      lsum[h] = lsum[h] * corr + psum;
#pragma unroll
      for (int nt = 0; nt < 4; ++nt)
#pragma unroll
        for (int r = 0; r < 4; ++r) acc[h][nt][r] *= corr;
      const short8 pf0 = *(const short8*)&P[wave][h * 16 + lo][hi * 8];
      short8 pf1;
      if (kclim == 4) pf1 = *(const short8*)&P[wave][h * 16 + lo][32 + hi * 8];
#pragma unroll
      for (int nt = 0; nt < 4; ++nt) {
        acc[h][nt] = mfma_bf16(pf0, vf[nt][0], acc[h][nt]);
        if (kclim == 4) acc[h][nt] = mfma_bf16(pf1, vf[nt][1], acc[h][nt]);
      }
    }
  };

  for (int it = 0; it < nfull; ++it)
    do_tile(it * 64, 4, false, true, (it + 1 < nfull) || tail4);
  if (tail4) do_tile(nfull * 64, 4, true, false, false);
  else       do_tile(nfull * 64, 2, true, false, false);

#pragma unroll
  for (int h = 0; h < 2; ++h) {
    lsum[h] += __shfl_xor(lsum[h], 16);
    lsum[h] += __shfl_xor(lsum[h], 32);
  }
  const int b = bh >> 4, hh = bh & 15;
#pragma unroll
  for (int h = 0; h < 2; ++h)
#pragma unroll
    for (int r = 0; r < 4; ++r) {
      const float linv = 1.0f / __shfl(lsum[h], hi * 4 + r);
      const int t = q0 + h * 16 + hi * 4 + r;
      const size_t base = ((size_t)(b * kT + t) * kH + hh) * kD;
#pragma unroll
      for (int nt = 0; nt < 4; ++nt)
        Y[base + nt * 16 + lo] = to_bf16(acc[h][nt][r] * linv);
    }
}

}  // namespace

extern "C" void kernel_launch(void* const* d_in, const int* in_sizes, int n_in,
                              void* d_out, int out_size, void* d_ws, size_t ws_size,
                              hipStream_t stream) {
  (void)in_sizes; (void)n_in; (void)out_size; (void)ws_size;
  const float* emb   = (const float*)d_in[0];
  const float* wqkv  = (const float*)d_in[1];
  const float* bqkv  = (const float*)d_in[2];
  const float* wproj = (const float*)d_in[3];
  const float* bproj = (const float*)d_in[4];
  float* out = (float*)d_out;

  char* p = (char*)d_ws;
  u16* embb   = (u16*)p; p += (size_t)kM * kC * 2;
  u16* wqkvt  = (u16*)p; p += (size_t)kNqkv * kC * 2;
  u16* wprojt = (u16*)p; p += (size_t)kC * kC * 2;
  u16* Qh     = (u16*)p; p += (size_t)kM * kC * 2;
  u16* Kh     = (u16*)p; p += (size_t)kM * kC * 2;
  u16* VTh    = (u16*)p; p += (size_t)kM * kC * 2;
  u16* Yh     = (u16*)p; p += (size_t)kM * kC * 2;

  const int n4 = kM * kC / 4;
  cvt_bf16_kernel<<<dim3((n4 + 255) / 256), 256, 0, stream>>>(emb, embb, n4);
  tconv_kernel<<<dim3(kNqkv / 32, kC / 32), dim3(32, 8), 0, stream>>>(wqkv, wqkvt, kC, kNqkv);
  tconv_kernel<<<dim3(kC / 32, kC / 32), dim3(32, 8), 0, stream>>>(wproj, wprojt, kC, kC);
  gemm_qkv<<<dim3(kNqkv / 128, kM / 256), 512, 0, stream>>>(
      embb, wqkvt, bqkv, Qh, Kh, VTh);
  attn_kernel<<<dim3(5 * kB * kH), 256, 0, stream>>>(Qh, Kh, VTh, Yh);
  gemm_proj<<<dim3(kC / 128, kM / 256), 512, 0, stream>>>(
      Yh, wprojt, bproj, out);
}